// Round 1
// baseline (1979.333 us; speedup 1.0000x reference)
//
#include <hip/hip_runtime.h>

constexpr int BB = 512, T = 128, N = 32, M = 16, P = 16;
constexpr int NP = N * P;   // 512
constexpr int NN = N * N;   // 1024

// ---------------- K1: serial forward Riccati (1 block, 256 thr) ----------------
__global__ __launch_bounds__(256) void k_fwd(
    const float* __restrict__ A, const float* __restrict__ C,
    const float* __restrict__ Q, const float* __restrict__ R,
    const float* __restrict__ Sigma0,
    float* __restrict__ K_all, float* __restrict__ Sp_all, float* __restrict__ Sf_all)
{
    __shared__ float A_l[N][N + 1], C_l[P][N + 1], Q_l[N][N + 1], R_l[P][P + 1];
    __shared__ float Sig[N][N + 1], Tmp[N][N + 1], Sp[N][N + 1], CP[P][N + 1];
    __shared__ float Aug[P][49];   // [S | CP] 16 x 48
    const int tid = threadIdx.x;

    for (int idx = tid; idx < NN; idx += 256) {
        A_l[idx >> 5][idx & 31] = A[idx];
        Q_l[idx >> 5][idx & 31] = Q[idx];
        Sig[idx >> 5][idx & 31] = Sigma0[idx];
    }
    for (int idx = tid; idx < P * N; idx += 256) C_l[idx >> 5][idx & 31] = C[idx];
    for (int idx = tid; idx < P * P; idx += 256) R_l[idx >> 4][idx & 15] = R[idx];
    __syncthreads();

    for (int t = 0; t < T; ++t) {
        // Tmp = A * Sig
        #pragma unroll
        for (int e = 0; e < 4; ++e) {
            int idx = tid + e * 256; int i = idx >> 5, j = idx & 31;
            float s = 0.f;
            #pragma unroll
            for (int k = 0; k < N; ++k) s += A_l[i][k] * Sig[k][j];
            Tmp[i][j] = s;
        }
        __syncthreads();
        // Sp = Tmp * A^T + Q ; store
        #pragma unroll
        for (int e = 0; e < 4; ++e) {
            int idx = tid + e * 256; int i = idx >> 5, j = idx & 31;
            float s = Q_l[i][j];
            #pragma unroll
            for (int k = 0; k < N; ++k) s += Tmp[i][k] * A_l[j][k];
            Sp[i][j] = s;
            Sp_all[t * NN + idx] = s;
        }
        __syncthreads();
        // CP = C * Sp
        #pragma unroll
        for (int e = 0; e < 2; ++e) {
            int idx = tid + e * 256; int p = idx >> 5, j = idx & 31;
            float s = 0.f;
            #pragma unroll
            for (int k = 0; k < N; ++k) s += C_l[p][k] * Sp[k][j];
            CP[p][j] = s;
        }
        __syncthreads();
        // S = CP*C^T + R  -> Aug[:, :16]; Aug[:, 16:48] = CP
        {
            int p = tid >> 4, q = tid & 15;
            float s = R_l[p][q];
            #pragma unroll
            for (int k = 0; k < N; ++k) s += CP[p][k] * C_l[q][k];
            Aug[p][q] = s;
        }
        #pragma unroll
        for (int e = 0; e < 2; ++e) {
            int idx = tid + e * 256; int p = idx >> 5, j = idx & 31;
            Aug[p][16 + j] = CP[p][j];
        }
        __syncthreads();
        // Gauss-Jordan on [S | CP] inside wave 0 (wave-synchronous, no barriers)
        if (tid < 64) {
            int r = tid >> 2, c0 = (tid & 3) * 12;
            for (int p = 0; p < P; ++p) {
                float pinv = 1.0f / Aug[p][p];
                float f = Aug[r][p];
                float prow[12], mine[12];
                #pragma unroll
                for (int c = 0; c < 12; ++c) { prow[c] = Aug[p][c0 + c]; mine[c] = Aug[r][c0 + c]; }
                float fp = f * pinv;
                #pragma unroll
                for (int c = 0; c < 12; ++c)
                    Aug[r][c0 + c] = (r == p) ? prow[c] * pinv : mine[c] - fp * prow[c];
            }
        }
        __syncthreads();
        // K[t][i][p] = X[p][i] = Aug[p][16+i]
        #pragma unroll
        for (int e = 0; e < 2; ++e) {
            int idx = tid + e * 256; int i = idx >> 4, p = idx & 15;
            K_all[t * NP + idx] = Aug[p][16 + i];
        }
        // Tmp = Sp - K * CP
        #pragma unroll
        for (int e = 0; e < 4; ++e) {
            int idx = tid + e * 256; int i = idx >> 5, j = idx & 31;
            float s = Sp[i][j];
            #pragma unroll
            for (int p = 0; p < P; ++p) s -= Aug[p][16 + i] * CP[p][j];
            Tmp[i][j] = s;
        }
        __syncthreads();
        // symmetrize -> Sig, store Sf
        #pragma unroll
        for (int e = 0; e < 4; ++e) {
            int idx = tid + e * 256; int i = idx >> 5, j = idx & 31;
            float v = 0.5f * (Tmp[i][j] + Tmp[j][i]);
            Sig[i][j] = v;
            Sf_all[t * NN + idx] = v;
        }
        __syncthreads();
    }
}

// ---------------- K2: J_t, H_t for t = 0..T-2 (parallel over t) ----------------
__global__ __launch_bounds__(256) void k_jh(
    const float* __restrict__ A,
    const float* __restrict__ Sp_all, const float* __restrict__ Sf_all,
    float* __restrict__ J_all, float* __restrict__ H_all)
{
    const int t = blockIdx.x;  // 0..T-2
    __shared__ float A_l[N][N + 1], Sf[N][N + 1], Sp1[N][N + 1];
    __shared__ float Aug[N][65], W[N][N + 1], Jl[N][N + 1];
    const int tid = threadIdx.x;

    for (int idx = tid; idx < NN; idx += 256) {
        A_l[idx >> 5][idx & 31] = A[idx];
        Sf[idx >> 5][idx & 31]  = Sf_all[t * NN + idx];
        Sp1[idx >> 5][idx & 31] = Sp_all[(t + 1) * NN + idx];
    }
    __syncthreads();
    // Aug = [Sp1 | A*Sf]
    #pragma unroll
    for (int e = 0; e < 4; ++e) {
        int idx = tid + e * 256; int i = idx >> 5, j = idx & 31;
        float s = 0.f;
        #pragma unroll
        for (int k = 0; k < N; ++k) s += A_l[i][k] * Sf[k][j];
        Aug[i][32 + j] = s;
        Aug[i][j] = Sp1[i][j];
    }
    __syncthreads();
    // GJ, 32 pivots, whole block
    {
        int r = tid >> 3, c0 = (tid & 7) * 8;
        for (int p = 0; p < N; ++p) {
            float pinv = 1.0f / Aug[p][p];
            float f = Aug[r][p];
            float prow[8], mine[8];
            #pragma unroll
            for (int c = 0; c < 8; ++c) { prow[c] = Aug[p][c0 + c]; mine[c] = Aug[r][c0 + c]; }
            __syncthreads();
            float fp = f * pinv;
            #pragma unroll
            for (int c = 0; c < 8; ++c)
                Aug[r][c0 + c] = (r == p) ? prow[c] * pinv : mine[c] - fp * prow[c];
            __syncthreads();
        }
    }
    // J[i][j] = G[j][i] = Aug[j][32+i]
    #pragma unroll
    for (int e = 0; e < 4; ++e) {
        int idx = tid + e * 256; int i = idx >> 5, j = idx & 31;
        float v = Aug[j][32 + i];
        Jl[i][j] = v;
        J_all[t * NN + idx] = v;
    }
    __syncthreads();
    // W = J * Sp1
    #pragma unroll
    for (int e = 0; e < 4; ++e) {
        int idx = tid + e * 256; int i = idx >> 5, j = idx & 31;
        float s = 0.f;
        #pragma unroll
        for (int k = 0; k < N; ++k) s += Jl[i][k] * Sp1[k][j];
        W[i][j] = s;
    }
    __syncthreads();
    // H = Sf - W * J^T
    #pragma unroll
    for (int e = 0; e < 4; ++e) {
        int idx = tid + e * 256; int i = idx >> 5, j = idx & 31;
        float s = Sf[i][j];
        #pragma unroll
        for (int k = 0; k < N; ++k) s -= W[i][k] * Jl[j][k];
        H_all[t * NN + idx] = s;
    }
}

// ---------------- K3: serial smoother covariance scan (1 block) ----------------
__global__ __launch_bounds__(256) void k_sscan(
    const float* __restrict__ Sf_all,
    const float* __restrict__ J_all, const float* __restrict__ H_all,
    float* __restrict__ Ss_all)
{
    __shared__ float Ss[N][N + 1], Jl[N][N + 1], W[N][N + 1], X[N][N + 1];
    const int tid = threadIdx.x;
    for (int idx = tid; idx < NN; idx += 256) {
        float v = Sf_all[(T - 1) * NN + idx];
        Ss[idx >> 5][idx & 31] = v;
        Ss_all[(T - 1) * NN + idx] = v;
    }
    __syncthreads();
    for (int t = T - 2; t >= 0; --t) {
        for (int idx = tid; idx < NN; idx += 256) Jl[idx >> 5][idx & 31] = J_all[t * NN + idx];
        __syncthreads();
        #pragma unroll
        for (int e = 0; e < 4; ++e) {
            int idx = tid + e * 256; int i = idx >> 5, j = idx & 31;
            float s = 0.f;
            #pragma unroll
            for (int k = 0; k < N; ++k) s += Jl[i][k] * Ss[k][j];
            W[i][j] = s;
        }
        __syncthreads();
        #pragma unroll
        for (int e = 0; e < 4; ++e) {
            int idx = tid + e * 256; int i = idx >> 5, j = idx & 31;
            float s = H_all[t * NN + idx];
            #pragma unroll
            for (int k = 0; k < N; ++k) s += W[i][k] * Jl[j][k];
            X[i][j] = s;
        }
        __syncthreads();
        #pragma unroll
        for (int e = 0; e < 4; ++e) {
            int idx = tid + e * 256; int i = idx >> 5, j = idx & 31;
            float v = 0.5f * (X[i][j] + X[j][i]);
            Ss[i][j] = v;
            Ss_all[t * NN + idx] = v;
        }
        __syncthreads();
    }
}

// ---------------- K4: per-batch mean filter + smoother (1 wave / batch) --------
__global__ __launch_bounds__(64) void k_mu(
    const float* __restrict__ Y, const float* __restrict__ U,
    const float* __restrict__ A, const float* __restrict__ Bm,
    const float* __restrict__ C, const float* __restrict__ mu0,
    const float* __restrict__ K_all, const float* __restrict__ J_all,
    float* __restrict__ out_mus)
{
    const int b = blockIdx.x;
    const int lane = threadIdx.x;
    __shared__ float mfh[T][N];                 // mu_f history (16 KB)
    __shared__ float mub[N], mpb[N], rb[P], yb[P], ub[P], db[N];
    __shared__ float kb[N][P + 1];
    __shared__ float jb[N][N + 1];

    float areg[N], breg[M], creg[N];
    if (lane < N) {
        #pragma unroll
        for (int j = 0; j < N; ++j) areg[j] = A[lane * N + j];
        #pragma unroll
        for (int p = 0; p < M; ++p) breg[p] = Bm[lane * M + p];
    }
    if (lane < P) {
        #pragma unroll
        for (int j = 0; j < N; ++j) creg[j] = C[lane * N + j];
    }
    float mu = (lane < N) ? mu0[lane] : 0.f;
    const float* Yb = Y + (size_t)b * T * P;
    const float* Ub = U + (size_t)b * T * M;

    for (int t = 0; t < T; ++t) {
        if (lane < N) {          // stage K_t coalesced -> LDS
            #pragma unroll
            for (int q = 0; q < P; ++q) { int f = lane + 32 * q; kb[f >> 4][f & 15] = K_all[t * NP + f]; }
        }
        if (lane < P) { yb[lane] = Yb[t * P + lane]; ub[lane] = Ub[t * M + lane]; }
        if (lane < N) mub[lane] = mu;
        float mp = 0.f;
        if (lane < N) {
            #pragma unroll
            for (int j = 0; j < N; ++j) mp += areg[j] * mub[j];
            #pragma unroll
            for (int p = 0; p < M; ++p) mp += breg[p] * ub[p];
            mpb[lane] = mp;
        }
        if (lane < P) {
            float r = yb[lane];
            #pragma unroll
            for (int j = 0; j < N; ++j) r -= creg[j] * mpb[j];
            rb[lane] = r;
        }
        if (lane < N) {
            float mf = mp;
            #pragma unroll
            for (int p = 0; p < P; ++p) mf += kb[lane][p] * rb[p];
            mfh[t][lane] = mf;
            mu = mf;
        }
    }
    // backward smoother for means
    if (lane < N) out_mus[((size_t)b * T + (T - 1)) * N + lane] = mu;
    float ms = mu;
    for (int t = T - 2; t >= 0; --t) {
        if (lane < N) {          // stage J_t coalesced -> LDS
            #pragma unroll
            for (int q = 0; q < N; ++q) { int f = lane + 32 * q; jb[f >> 5][f & 31] = J_all[t * NN + f]; }
        }
        if (lane < P) ub[lane] = Ub[(t + 1) * M + lane];
        if (lane < N) {
            float mp1 = 0.f;
            #pragma unroll
            for (int j = 0; j < N; ++j) mp1 += areg[j] * mfh[t][j];
            #pragma unroll
            for (int p = 0; p < M; ++p) mp1 += breg[p] * ub[p];
            db[lane] = ms - mp1;
        }
        if (lane < N) {
            float v = mfh[t][lane];
            #pragma unroll
            for (int j = 0; j < N; ++j) v += jb[lane][j] * db[j];
            ms = v;
            out_mus[((size_t)b * T + t) * N + lane] = v;
        }
    }
}

// ---------------- K5: broadcast Sig_s tiles to all batches (stream write) ------
__global__ __launch_bounds__(256) void k_bcast(
    const float* __restrict__ Ss_all, float4* __restrict__ out4)
{
    const float4* src = (const float4*)Ss_all;
    const long long total = (long long)BB * T * (NN / 4);
    const long long stride = (long long)gridDim.x * blockDim.x;
    for (long long g = blockIdx.x * (long long)blockDim.x + threadIdx.x; g < total; g += stride) {
        int e4 = (int)(g & 255);          // 256 float4 per (b,t) tile
        long long bt = g >> 8;
        int t = (int)(bt & (T - 1));      // T = 128, power of two
        out4[g] = src[t * 256 + e4];
    }
}

extern "C" void kernel_launch(void* const* d_in, const int* in_sizes, int n_in,
                              void* d_out, int out_size, void* d_ws, size_t ws_size,
                              hipStream_t stream)
{
    (void)in_sizes; (void)n_in; (void)out_size; (void)ws_size;
    const float* Y      = (const float*)d_in[0];
    const float* U      = (const float*)d_in[1];
    const float* A      = (const float*)d_in[2];
    const float* Bm     = (const float*)d_in[3];
    const float* C      = (const float*)d_in[4];
    const float* mu0    = (const float*)d_in[5];
    const float* Sigma0 = (const float*)d_in[6];
    const float* Q      = (const float*)d_in[7];
    const float* R      = (const float*)d_in[8];

    float* ws     = (float*)d_ws;
    float* K_all  = ws;                       // T*N*P      = 65536
    float* Sp_all = K_all + T * NP;           // T*N*N      = 131072
    float* Sf_all = Sp_all + T * NN;
    float* J_all  = Sf_all + T * NN;
    float* H_all  = J_all + T * NN;
    float* Ss_all = H_all + T * NN;           // total ~2.8 MB

    float* out_mus  = (float*)d_out;
    float* out_sigs = out_mus + (size_t)BB * T * N;

    hipLaunchKernelGGL(k_fwd,   dim3(1),     dim3(256), 0, stream, A, C, Q, R, Sigma0, K_all, Sp_all, Sf_all);
    hipLaunchKernelGGL(k_jh,    dim3(T - 1), dim3(256), 0, stream, A, Sp_all, Sf_all, J_all, H_all);
    hipLaunchKernelGGL(k_sscan, dim3(1),     dim3(256), 0, stream, Sf_all, J_all, H_all, Ss_all);
    hipLaunchKernelGGL(k_mu,    dim3(BB),    dim3(64),  0, stream, Y, U, A, Bm, C, mu0, K_all, J_all, out_mus);
    hipLaunchKernelGGL(k_bcast, dim3(4096),  dim3(256), 0, stream, Ss_all, (float4*)out_sigs);
}

// Round 4
// 1433.289 us; speedup vs baseline: 1.3810x; 1.3810x over previous
//
#include <hip/hip_runtime.h>

constexpr int BB = 512, T = 128, N = 32, M = 16, P = 16;
constexpr int NP = N * P;   // 512
constexpr int NN = N * N;   // 1024

// ---------------- K1: serial forward Riccati (1 block, 256 thr) ----------------
// Round-1 structure (scalar padded LDS, same barriers, same wave0 GJ, same
// symmetrize). Deltas vs round 1 (each provably equivalent):
//  - immutable A/C/Q/R rows hoisted LDS->regs once after init barrier
//  - phase B computes the transposed output element (exact same formula)
__global__ __launch_bounds__(256) void k_fwd(
    const float* __restrict__ A, const float* __restrict__ C,
    const float* __restrict__ Q, const float* __restrict__ R,
    const float* __restrict__ Sigma0,
    float* __restrict__ K_all, float* __restrict__ Sp_all, float* __restrict__ Sf_all)
{
    __shared__ float A_l[N][N + 1], C_l[P][N + 1], Q_l[N][N + 1], R_l[P][P + 1];
    __shared__ float Sig[N][N + 1], Tmp[N][N + 1], Sp[N][N + 1], CP[P][N + 1];
    __shared__ float Aug[P][49];   // [S | CP] 16 x 48
    const int tid = threadIdx.x;
    const int i0 = tid >> 5, j = tid & 31;   // thread owns column j, rows i0+8e
    const int pD = tid >> 4, q = tid & 15;   // S-element (pD, q)

    for (int idx = tid; idx < NN; idx += 256) {
        A_l[idx >> 5][idx & 31] = A[idx];
        Q_l[idx >> 5][idx & 31] = Q[idx];
        Sig[idx >> 5][idx & 31] = Sigma0[idx];
    }
    for (int idx = tid; idx < P * N; idx += 256) C_l[idx >> 5][idx & 31] = C[idx];
    for (int idx = tid; idx < P * P; idx += 256) R_l[idx >> 4][idx & 15] = R[idx];
    __syncthreads();

    // hoist immutable data to regs (pure reads of never-again-written LDS)
    float Arow[4][32], Ajrow[32], Cq[32], Qv[4], Qjv[4];
    #pragma unroll
    for (int e = 0; e < 4; ++e) {
        #pragma unroll
        for (int k = 0; k < 32; ++k) Arow[e][k] = A_l[i0 + 8*e][k];
        Qv[e]  = Q_l[i0 + 8*e][j];
        Qjv[e] = Q_l[j][i0 + 8*e];
    }
    #pragma unroll
    for (int k = 0; k < 32; ++k) { Ajrow[k] = A_l[j][k]; Cq[k] = C_l[q][k]; }
    const float Rv = R_l[pD][q];
    (void)Qv; (void)Ajrow;

    for (int t = 0; t < T; ++t) {
        // A: Tmp[i][j] = sum_k A[i][k] * Sig[k][j]
        {
            float sc[32];
            #pragma unroll
            for (int k = 0; k < 32; ++k) sc[k] = Sig[k][j];
            #pragma unroll
            for (int e = 0; e < 4; ++e) {
                float s = 0.f;
                #pragma unroll
                for (int k = 0; k < 32; ++k) s += Arow[e][k] * sc[k];
                Tmp[i0 + 8*e][j] = s;
            }
        }
        __syncthreads();
        // B (transposed output): Sp[j][c] = Q[j][c] + sum_k Tmp[j][k]*A[c][k], c=i0+8e
        {
            float tr[32];
            #pragma unroll
            for (int k = 0; k < 32; ++k) tr[k] = Tmp[j][k];
            #pragma unroll
            for (int e = 0; e < 4; ++e) {
                const int c = i0 + 8*e;
                float s = Qjv[e];
                #pragma unroll
                for (int k = 0; k < 32; ++k) s += tr[k] * Arow[e][k];
                Sp[j][c] = s;
                Sp_all[t * NN + j * 32 + c] = s;
            }
        }
        __syncthreads();
        // C: CP[p][j] = sum_k C[p][k] * Sp[k][j]   (p = i0, i0+8)
        {
            float spc[32];
            #pragma unroll
            for (int k = 0; k < 32; ++k) spc[k] = Sp[k][j];
            #pragma unroll
            for (int e = 0; e < 2; ++e) {
                const int p = i0 + 8*e;
                float s = 0.f;
                #pragma unroll
                for (int k = 0; k < 32; ++k) s += C_l[p][k] * spc[k];
                CP[p][j] = s;
            }
        }
        __syncthreads();
        // D: S[pD][q] = sum_k CP[pD][k]*C[q][k] + R ; copy CP into Aug
        {
            float cpr[32];
            #pragma unroll
            for (int k = 0; k < 32; ++k) cpr[k] = CP[pD][k];
            float s = Rv;
            #pragma unroll
            for (int k = 0; k < 32; ++k) s += cpr[k] * Cq[k];
            Aug[pD][q] = s;
        }
        #pragma unroll
        for (int e = 0; e < 2; ++e) {
            const int p = i0 + 8*e;
            Aug[p][16 + j] = CP[p][j];
        }
        __syncthreads();
        // Gauss-Jordan on [S | CP] inside wave 0 — round-1 verbatim
        if (tid < 64) {
            int r = tid >> 2, c0 = (tid & 3) * 12;
            for (int p = 0; p < P; ++p) {
                float pinv = 1.0f / Aug[p][p];
                float f = Aug[r][p];
                float prow[12], mine[12];
                #pragma unroll
                for (int c = 0; c < 12; ++c) { prow[c] = Aug[p][c0 + c]; mine[c] = Aug[r][c0 + c]; }
                float fp = f * pinv;
                #pragma unroll
                for (int c = 0; c < 12; ++c)
                    Aug[r][c0 + c] = (r == p) ? prow[c] * pinv : mine[c] - fp * prow[c];
            }
        }
        __syncthreads();
        // K[t][i][p] = Aug[p][16+i]
        #pragma unroll
        for (int e = 0; e < 2; ++e) {
            const int idx = tid + 256*e;
            K_all[t * NP + idx] = Aug[idx & 15][16 + (idx >> 4)];
        }
        // Sig_f (pre-sym) -> Tmp: Tmp[i][j] = Sp[i][j] - sum_p K[i][p]*CP[p][j]
        {
            float cpj[16];
            #pragma unroll
            for (int p = 0; p < 16; ++p) cpj[p] = CP[p][j];
            #pragma unroll
            for (int e = 0; e < 4; ++e) {
                const int i = i0 + 8*e;
                float s = Sp[i][j];
                #pragma unroll
                for (int p = 0; p < 16; ++p) s -= Aug[p][16 + i] * cpj[p];
                Tmp[i][j] = s;
            }
        }
        __syncthreads();
        // symmetrize -> Sig, store Sf  (round-1 verbatim)
        #pragma unroll
        for (int e = 0; e < 4; ++e) {
            const int i = i0 + 8*e;
            const float v = 0.5f * (Tmp[i][j] + Tmp[j][i]);
            Sig[i][j] = v;
            Sf_all[t * NN + tid + 256*e] = v;
        }
        __syncthreads();
    }
}

// ---------------- K2: J_t, H_t for t = 0..T-2 (parallel over t) ----------------
// round-1 verbatim (passed)
__global__ __launch_bounds__(256) void k_jh(
    const float* __restrict__ A,
    const float* __restrict__ Sp_all, const float* __restrict__ Sf_all,
    float* __restrict__ J_all, float* __restrict__ H_all)
{
    const int t = blockIdx.x;  // 0..T-2
    __shared__ float A_l[N][N + 1], Sf[N][N + 1], Sp1[N][N + 1];
    __shared__ float Aug[N][65], W[N][N + 1], Jl[N][N + 1];
    const int tid = threadIdx.x;

    for (int idx = tid; idx < NN; idx += 256) {
        A_l[idx >> 5][idx & 31] = A[idx];
        Sf[idx >> 5][idx & 31]  = Sf_all[t * NN + idx];
        Sp1[idx >> 5][idx & 31] = Sp_all[(t + 1) * NN + idx];
    }
    __syncthreads();
    #pragma unroll
    for (int e = 0; e < 4; ++e) {
        int idx = tid + e * 256; int i = idx >> 5, j = idx & 31;
        float s = 0.f;
        #pragma unroll
        for (int k = 0; k < N; ++k) s += A_l[i][k] * Sf[k][j];
        Aug[i][32 + j] = s;
        Aug[i][j] = Sp1[i][j];
    }
    __syncthreads();
    {
        int r = tid >> 3, c0 = (tid & 7) * 8;
        for (int p = 0; p < N; ++p) {
            float pinv = 1.0f / Aug[p][p];
            float f = Aug[r][p];
            float prow[8], mine[8];
            #pragma unroll
            for (int c = 0; c < 8; ++c) { prow[c] = Aug[p][c0 + c]; mine[c] = Aug[r][c0 + c]; }
            __syncthreads();
            float fp = f * pinv;
            #pragma unroll
            for (int c = 0; c < 8; ++c)
                Aug[r][c0 + c] = (r == p) ? prow[c] * pinv : mine[c] - fp * prow[c];
            __syncthreads();
        }
    }
    #pragma unroll
    for (int e = 0; e < 4; ++e) {
        int idx = tid + e * 256; int i = idx >> 5, j = idx & 31;
        float v = Aug[j][32 + i];
        Jl[i][j] = v;
        J_all[t * NN + idx] = v;
    }
    __syncthreads();
    #pragma unroll
    for (int e = 0; e < 4; ++e) {
        int idx = tid + e * 256; int i = idx >> 5, j = idx & 31;
        float s = 0.f;
        #pragma unroll
        for (int k = 0; k < N; ++k) s += Jl[i][k] * Sp1[k][j];
        W[i][j] = s;
    }
    __syncthreads();
    #pragma unroll
    for (int e = 0; e < 4; ++e) {
        int idx = tid + e * 256; int i = idx >> 5, j = idx & 31;
        float s = Sf[i][j];
        #pragma unroll
        for (int k = 0; k < N; ++k) s -= W[i][k] * Jl[j][k];
        H_all[t * NN + idx] = s;
    }
}

// ---------------- K3: serial smoother covariance scan (1 block) ----------------
// Round-1 barrier skeleton; J rows read straight from global into regs
// (the pattern k_mu uses), H staged coalesced via LDS, transposed-output X.
__global__ __launch_bounds__(256) void k_sscan(
    const float* __restrict__ Sf_all,
    const float* __restrict__ J_all, const float* __restrict__ H_all,
    float* __restrict__ Ss_all)
{
    __shared__ float Ss[N][N + 1], W[N][N + 1], X[N][N + 1], Hl[N][N + 1];
    const int tid = threadIdx.x;
    const int i0 = tid >> 5, j = tid & 31;

    for (int idx = tid; idx < NN; idx += 256) {
        float v = Sf_all[(size_t)(T - 1) * NN + idx];
        Ss[idx >> 5][idx & 31] = v;
        Ss_all[(size_t)(T - 1) * NN + idx] = v;
    }
    __syncthreads();

    for (int t = T - 2; t >= 0; --t) {
        // J rows i0+8e from global (rows shared by 32 threads -> L1 broadcast)
        float jr[4][32];
        #pragma unroll
        for (int e = 0; e < 4; ++e) {
            const float4* r4 = reinterpret_cast<const float4*>(J_all + (size_t)t * NN + (i0 + 8*e) * 32);
            #pragma unroll
            for (int c = 0; c < 8; ++c) {
                float4 v = r4[c];
                jr[e][4*c+0] = v.x; jr[e][4*c+1] = v.y; jr[e][4*c+2] = v.z; jr[e][4*c+3] = v.w;
            }
        }
        // stage H coalesced -> LDS (read transposed in X phase)
        #pragma unroll
        for (int e = 0; e < 4; ++e)
            Hl[i0 + 8*e][j] = H_all[(size_t)t * NN + tid + 256*e];
        // W[i][j] = sum_k J[i][k] * Ss[k][j]
        {
            float sc[32];
            #pragma unroll
            for (int k = 0; k < 32; ++k) sc[k] = Ss[k][j];
            #pragma unroll
            for (int e = 0; e < 4; ++e) {
                float s = 0.f;
                #pragma unroll
                for (int k = 0; k < 32; ++k) s += jr[e][k] * sc[k];
                W[i0 + 8*e][j] = s;
            }
        }
        __syncthreads();
        // X[j][c] = H[j][c] + sum_k W[j][k] * J[c][k],  c = i0+8e
        {
            float wr[32];
            #pragma unroll
            for (int k = 0; k < 32; ++k) wr[k] = W[j][k];
            #pragma unroll
            for (int e = 0; e < 4; ++e) {
                const int c = i0 + 8*e;
                float s = Hl[j][c];
                #pragma unroll
                for (int k = 0; k < 32; ++k) s += wr[k] * jr[e][k];
                X[j][c] = s;
            }
        }
        __syncthreads();
        // symmetrize -> Ss, store
        #pragma unroll
        for (int e = 0; e < 4; ++e) {
            const int i = i0 + 8*e;
            const float v = 0.5f * (X[i][j] + X[j][i]);
            Ss[i][j] = v;
            Ss_all[(size_t)t * NN + tid + 256*e] = v;
        }
        __syncthreads();
    }
}

// ---------------- K4: per-batch mean filter + smoother (1 wave / batch) --------
// round-1 verbatim (passed)
__global__ __launch_bounds__(64) void k_mu(
    const float* __restrict__ Y, const float* __restrict__ U,
    const float* __restrict__ A, const float* __restrict__ Bm,
    const float* __restrict__ C, const float* __restrict__ mu0,
    const float* __restrict__ K_all, const float* __restrict__ J_all,
    float* __restrict__ out_mus)
{
    const int b = blockIdx.x;
    const int lane = threadIdx.x;
    __shared__ float mfh[T][N];
    __shared__ float mub[N], mpb[N], rb[P], yb[P], ub[P], db[N];
    __shared__ float kb[N][P + 1];
    __shared__ float jb[N][N + 1];

    float areg[N], breg[M], creg[N];
    if (lane < N) {
        #pragma unroll
        for (int j = 0; j < N; ++j) areg[j] = A[lane * N + j];
        #pragma unroll
        for (int p = 0; p < M; ++p) breg[p] = Bm[lane * M + p];
    }
    if (lane < P) {
        #pragma unroll
        for (int j = 0; j < N; ++j) creg[j] = C[lane * N + j];
    }
    float mu = (lane < N) ? mu0[lane] : 0.f;
    const float* Yb = Y + (size_t)b * T * P;
    const float* Ub = U + (size_t)b * T * M;

    for (int t = 0; t < T; ++t) {
        if (lane < N) {
            #pragma unroll
            for (int q = 0; q < P; ++q) { int f = lane + 32 * q; kb[f >> 4][f & 15] = K_all[t * NP + f]; }
        }
        if (lane < P) { yb[lane] = Yb[t * P + lane]; ub[lane] = Ub[t * M + lane]; }
        if (lane < N) mub[lane] = mu;
        float mp = 0.f;
        if (lane < N) {
            #pragma unroll
            for (int j = 0; j < N; ++j) mp += areg[j] * mub[j];
            #pragma unroll
            for (int p = 0; p < M; ++p) mp += breg[p] * ub[p];
            mpb[lane] = mp;
        }
        if (lane < P) {
            float r = yb[lane];
            #pragma unroll
            for (int j = 0; j < N; ++j) r -= creg[j] * mpb[j];
            rb[lane] = r;
        }
        if (lane < N) {
            float mf = mp;
            #pragma unroll
            for (int p = 0; p < P; ++p) mf += kb[lane][p] * rb[p];
            mfh[t][lane] = mf;
            mu = mf;
        }
    }
    if (lane < N) out_mus[((size_t)b * T + (T - 1)) * N + lane] = mu;
    float ms = mu;
    for (int t = T - 2; t >= 0; --t) {
        if (lane < N) {
            #pragma unroll
            for (int q = 0; q < N; ++q) { int f = lane + 32 * q; jb[f >> 5][f & 31] = J_all[t * NN + f]; }
        }
        if (lane < P) ub[lane] = Ub[(t + 1) * M + lane];
        if (lane < N) {
            float mp1 = 0.f;
            #pragma unroll
            for (int j = 0; j < N; ++j) mp1 += areg[j] * mfh[t][j];
            #pragma unroll
            for (int p = 0; p < M; ++p) mp1 += breg[p] * ub[p];
            db[lane] = ms - mp1;
        }
        if (lane < N) {
            float v = mfh[t][lane];
            #pragma unroll
            for (int j = 0; j < N; ++j) v += jb[lane][j] * db[j];
            ms = v;
            out_mus[((size_t)b * T + t) * N + lane] = v;
        }
    }
}

// ---------------- K5: broadcast Sig_s tiles to all batches (stream write) ------
__global__ __launch_bounds__(256) void k_bcast(
    const float* __restrict__ Ss_all, float4* __restrict__ out4)
{
    const float4* src = (const float4*)Ss_all;
    const long long total = (long long)BB * T * (NN / 4);
    const long long stride = (long long)gridDim.x * blockDim.x;
    for (long long g = blockIdx.x * (long long)blockDim.x + threadIdx.x; g < total; g += stride) {
        int e4 = (int)(g & 255);
        long long bt = g >> 8;
        int t = (int)(bt & (T - 1));
        out4[g] = src[t * 256 + e4];
    }
}

extern "C" void kernel_launch(void* const* d_in, const int* in_sizes, int n_in,
                              void* d_out, int out_size, void* d_ws, size_t ws_size,
                              hipStream_t stream)
{
    (void)in_sizes; (void)n_in; (void)out_size; (void)ws_size;
    const float* Y      = (const float*)d_in[0];
    const float* U      = (const float*)d_in[1];
    const float* A      = (const float*)d_in[2];
    const float* Bm     = (const float*)d_in[3];
    const float* C      = (const float*)d_in[4];
    const float* mu0    = (const float*)d_in[5];
    const float* Sigma0 = (const float*)d_in[6];
    const float* Q      = (const float*)d_in[7];
    const float* R      = (const float*)d_in[8];

    float* ws     = (float*)d_ws;
    float* K_all  = ws;
    float* Sp_all = K_all + T * NP;
    float* Sf_all = Sp_all + T * NN;
    float* J_all  = Sf_all + T * NN;
    float* H_all  = J_all + T * NN;
    float* Ss_all = H_all + T * NN;

    float* out_mus  = (float*)d_out;
    float* out_sigs = out_mus + (size_t)BB * T * N;

    hipLaunchKernelGGL(k_fwd,   dim3(1),     dim3(256), 0, stream, A, C, Q, R, Sigma0, K_all, Sp_all, Sf_all);
    hipLaunchKernelGGL(k_jh,    dim3(T - 1), dim3(256), 0, stream, A, Sp_all, Sf_all, J_all, H_all);
    hipLaunchKernelGGL(k_sscan, dim3(1),     dim3(256), 0, stream, Sf_all, J_all, H_all, Ss_all);
    hipLaunchKernelGGL(k_mu,    dim3(BB),    dim3(64),  0, stream, Y, U, A, Bm, C, mu0, K_all, J_all, out_mus);
    hipLaunchKernelGGL(k_bcast, dim3(4096),  dim3(256), 0, stream, Ss_all, (float4*)out_sigs);
}